// Round 1
// baseline (314.497 us; speedup 1.0000x reference)
//
#include <hip/hip_runtime.h>

typedef unsigned short u16;
typedef unsigned int u32;
typedef float f32x4 __attribute__((ext_vector_type(4)));
typedef short s16x8 __attribute__((ext_vector_type(8)));

#define LSEQ 2048
#define NBATCH 8
#define QIN 512
#define VIN 1024
#define KCAT 704
#define KEFF 2560
#define NORMS 0.10206207261596575f  // 1/sqrt(96)

__device__ __forceinline__ u16 f2bf(float f) {
  u32 u = __float_as_uint(f);
  u = (u + 0x7fffu + ((u >> 16) & 1u)) >> 16;  // RNE
  return (u16)u;
}

__device__ __forceinline__ s16x8 load8cvt(const float* __restrict__ p) {
  float4 a = *(const float4*)p;
  float4 b = *(const float4*)(p + 4);
  s16x8 r;
  r[0] = (short)f2bf(a.x); r[1] = (short)f2bf(a.y);
  r[2] = (short)f2bf(a.z); r[3] = (short)f2bf(a.w);
  r[4] = (short)f2bf(b.x); r[5] = (short)f2bf(b.y);
  r[6] = (short)f2bf(b.z); r[7] = (short)f2bf(b.w);
  return r;
}

// ---------------------------------------------------------------------------
// Kernel 1: fold conv3/conv5 + k_w into W_eff (96 x 2560 bf16) + b_eff, and
// convert q_w / v_w to bf16.  k index = t*512 + c, taps t=0..4 <-> offset t-2.
// ---------------------------------------------------------------------------
__global__ __launch_bounds__(256) void prep_kernel(
    const float* __restrict__ q_w, const float* __restrict__ k_w,
    const float* __restrict__ k_b, const float* __restrict__ v_w,
    const float* __restrict__ cn3_w, const float* __restrict__ cn3_b,
    const float* __restrict__ cn5_w, const float* __restrict__ cn5_b,
    u16* __restrict__ weff, float* __restrict__ beff,
    u16* __restrict__ qwb, u16* __restrict__ vwb) {
  int blk = blockIdx.x, tid = threadIdx.x;
  if (blk < 960) {                      // W_eff: 96*2560 = 245760 elems
    int e = blk * 256 + tid;
    int o = e / KEFF;
    int k = e % KEFF;
    int t = k >> 9;
    int c = k & 511;
    const float* kwo = k_w + o * KCAT;
    float acc = (t == 2) ? kwo[c] : 0.f;
    if (t >= 1 && t <= 3) {
      const float* c3 = cn3_w + c * 3 + (t - 1);   // cn3_w[j][c][t-1]
      #pragma unroll 4
      for (int j = 0; j < 96; ++j) acc += kwo[512 + j] * c3[j * 1536];
    }
    const float* c5 = cn5_w + c * 5 + t;           // cn5_w[j][c][t]
    #pragma unroll 4
    for (int j = 0; j < 96; ++j) acc += kwo[608 + j] * c5[j * 2560];
    weff[e] = f2bf(acc);
  } else if (blk == 960) {              // b_eff
    if (tid < 96) {
      const float* kwo = k_w + tid * KCAT;
      float b = k_b[tid];
      for (int j = 0; j < 96; ++j)
        b += kwo[512 + j] * cn3_b[j] + kwo[608 + j] * cn5_b[j];
      beff[tid] = b;
    }
  } else if (blk < 961 + 192) {         // q_w -> bf16 (49152)
    int i = (blk - 961) * 256 + tid;
    qwb[i] = f2bf(q_w[i]);
  } else {                              // v_w -> bf16 (98304)
    int i = (blk - 1153) * 256 + tid;
    vwb[i] = f2bf(v_w[i]);
  }
}

// ---------------------------------------------------------------------------
// Kernel 2: plain projection GEMM  Out[M=16384, N=96] = X[M,KD] @ W[N,KD]^T
// grid (32, 8) = (row-tile-in-batch, batch); block 256 = 4 waves x 16 rows.
// ---------------------------------------------------------------------------
template <int KD, bool WRF32>
__global__ __launch_bounds__(256) void proj_gemm(
    const float* __restrict__ X, const u16* __restrict__ W,
    const float* __restrict__ bias, u16* __restrict__ Out,
    float* __restrict__ OutF) {
  int bx = blockIdx.x, bb = blockIdx.y;
  int tid = threadIdx.x;
  int wid = tid >> 6, lane = tid & 63, ln = lane & 15, kg = lane >> 4;
  int row = bb * LSEQ + bx * 64 + wid * 16 + ln;
  const float* xr = X + (size_t)row * KD;
  f32x4 acc[6];
  #pragma unroll
  for (int nt = 0; nt < 6; ++nt) acc[nt] = (f32x4){0.f, 0.f, 0.f, 0.f};
  for (int kc = 0; kc < KD / 32; ++kc) {
    int k0 = kc * 32 + kg * 8;
    s16x8 a = load8cvt(xr + k0);
    #pragma unroll
    for (int nt = 0; nt < 6; ++nt) {
      s16x8 bf = *(const s16x8*)&W[(size_t)(nt * 16 + ln) * KD + k0];
      acc[nt] = __builtin_amdgcn_mfma_f32_16x16x32_bf16(a, bf, acc[nt], 0, 0, 0);
    }
  }
  int rowd = bb * LSEQ + bx * 64 + wid * 16 + kg * 4;  // D-frag rows
  #pragma unroll
  for (int nt = 0; nt < 6; ++nt) {
    int col = nt * 16 + ln;
    float bv = bias[col];
    #pragma unroll
    for (int r = 0; r < 4; ++r) {
      float v = acc[nt][r] + bv;
      size_t oi = (size_t)(rowd + r) * 96 + col;
      Out[oi] = f2bf(v);
      if (WRF32) OutF[oi] = v;
    }
  }
}

// ---------------------------------------------------------------------------
// Kernel 3: K projection as a 5-tap windowed GEMM over W_eff (K-dim 2560).
// Window rows clamped to the batch (SAME zero padding).
// ---------------------------------------------------------------------------
__global__ __launch_bounds__(256) void proj_kconv(
    const float* __restrict__ X, const u16* __restrict__ W,
    const float* __restrict__ bias, u16* __restrict__ Out) {
  int bx = blockIdx.x, bb = blockIdx.y;
  int tid = threadIdx.x;
  int wid = tid >> 6, lane = tid & 63, ln = lane & 15, kg = lane >> 4;
  int lrow = bx * 64 + wid * 16 + ln;  // local row in batch
  const float* xb = X + (size_t)bb * LSEQ * QIN;
  f32x4 acc[6];
  #pragma unroll
  for (int nt = 0; nt < 6; ++nt) acc[nt] = (f32x4){0.f, 0.f, 0.f, 0.f};
  for (int kc = 0; kc < KEFF / 32; ++kc) {
    int k0 = kc * 32 + kg * 8;
    int t = k0 >> 9;
    int c = k0 & 511;
    int sr = lrow + t - 2;
    s16x8 a;
    if (sr >= 0 && sr < LSEQ)
      a = load8cvt(xb + (size_t)sr * QIN + c);
    else
      a = (s16x8){0, 0, 0, 0, 0, 0, 0, 0};
    #pragma unroll
    for (int nt = 0; nt < 6; ++nt) {
      s16x8 bf = *(const s16x8*)&W[(size_t)(nt * 16 + ln) * KEFF + k0];
      acc[nt] = __builtin_amdgcn_mfma_f32_16x16x32_bf16(a, bf, acc[nt], 0, 0, 0);
    }
  }
  int rowd = bb * LSEQ + bx * 64 + wid * 16 + kg * 4;
  #pragma unroll
  for (int nt = 0; nt < 6; ++nt) {
    int col = nt * 16 + ln;
    float bv = bias[col];
    #pragma unroll
    for (int r = 0; r < 4; ++r) {
      size_t oi = (size_t)(rowd + r) * 96 + col;
      Out[oi] = f2bf(acc[nt][r] + bv);
    }
  }
}

// ---------------------------------------------------------------------------
// Kernel 4: flash attention + "+V".  grid (64, 8): 32 Q-rows per block,
// 2 waves x 16 rows.  Keys masked at >= seqlen[b]; queries never masked.
// ---------------------------------------------------------------------------
__global__ __launch_bounds__(128) void attn_kernel(
    const u16* __restrict__ Qb, const u16* __restrict__ Kb,
    const u16* __restrict__ Vb, const float* __restrict__ Vf,
    const int* __restrict__ seqlen, float* __restrict__ out) {
  __shared__ u16 Ks[32 * 104];   // K tile, padded stride 104
  __shared__ u16 Vt[96 * 40];    // V tile transposed [vd][key], stride 40
  __shared__ u16 Ps[2 * 16 * 40];  // per-wave P scratch

  int bx = blockIdx.x, bb = blockIdx.y;
  int tid = threadIdx.x;
  int wid = tid >> 6, lane = tid & 63, ln = lane & 15, kg = lane >> 4;
  int n = seqlen[bb];
  int nkc = (n + 31) >> 5;

  int qrow = bb * LSEQ + bx * 32 + wid * 16 + ln;
  s16x8 aQ[3];
  #pragma unroll
  for (int kk = 0; kk < 3; ++kk)
    aQ[kk] = *(const s16x8*)&Qb[(size_t)qrow * 96 + kk * 32 + kg * 8];

  float m[4], lsum[4];
  f32x4 acc[6];
  #pragma unroll
  for (int r = 0; r < 4; ++r) { m[r] = -INFINITY; lsum[r] = 0.f; }
  #pragma unroll
  for (int nt = 0; nt < 6; ++nt) acc[nt] = (f32x4){0.f, 0.f, 0.f, 0.f};

  const u16* Kbase = Kb + (size_t)bb * LSEQ * 96;
  const u16* Vbase = Vb + (size_t)bb * LSEQ * 96;

  for (int kc = 0; kc < nkc; ++kc) {
    int key0 = kc * 32;
    // ---- stage K (row-major) and V (transposed) into LDS ----
    #pragma unroll
    for (int c = 0; c < 6; ++c) {
      int idx = tid + c * 128;          // 0..767, 4 halves each
      int key = idx / 24;
      int dd = (idx % 24) * 4;
      uint2 kk2 = *(const uint2*)&Kbase[(size_t)(key0 + key) * 96 + dd];
      *(uint2*)&Ks[key * 104 + dd] = kk2;
      uint2 vv2 = *(const uint2*)&Vbase[(size_t)(key0 + key) * 96 + dd];
      Vt[(dd + 0) * 40 + key] = (u16)(vv2.x & 0xffffu);
      Vt[(dd + 1) * 40 + key] = (u16)(vv2.x >> 16);
      Vt[(dd + 2) * 40 + key] = (u16)(vv2.y & 0xffffu);
      Vt[(dd + 3) * 40 + key] = (u16)(vv2.y >> 16);
    }
    __syncthreads();

    // ---- S = Q K^T (two 16x16 n-tiles over 32 keys) ----
    f32x4 s0 = (f32x4){0.f, 0.f, 0.f, 0.f};
    f32x4 s1 = (f32x4){0.f, 0.f, 0.f, 0.f};
    #pragma unroll
    for (int kk = 0; kk < 3; ++kk) {
      s16x8 b0 = *(const s16x8*)&Ks[ln * 104 + kk * 32 + kg * 8];
      s0 = __builtin_amdgcn_mfma_f32_16x16x32_bf16(aQ[kk], b0, s0, 0, 0, 0);
      s16x8 b1 = *(const s16x8*)&Ks[(16 + ln) * 104 + kk * 32 + kg * 8];
      s1 = __builtin_amdgcn_mfma_f32_16x16x32_bf16(aQ[kk], b1, s1, 0, 0, 0);
    }

    // ---- mask + scale, online softmax ----
    bool v0 = (key0 + ln) < n;
    bool v1 = (key0 + 16 + ln) < n;
    float sv0[4], sv1[4], mx[4];
    #pragma unroll
    for (int r = 0; r < 4; ++r) {
      sv0[r] = v0 ? s0[r] * NORMS : -1e30f;
      sv1[r] = v1 ? s1[r] * NORMS : -1e30f;
      mx[r] = fmaxf(sv0[r], sv1[r]);
    }
    #pragma unroll
    for (int r = 0; r < 4; ++r) {
      mx[r] = fmaxf(mx[r], __shfl_xor(mx[r], 1, 16));
      mx[r] = fmaxf(mx[r], __shfl_xor(mx[r], 2, 16));
      mx[r] = fmaxf(mx[r], __shfl_xor(mx[r], 4, 16));
      mx[r] = fmaxf(mx[r], __shfl_xor(mx[r], 8, 16));
    }
    float fac[4], p0[4], p1[4], rs[4];
    #pragma unroll
    for (int r = 0; r < 4; ++r) {
      float mn = fmaxf(m[r], mx[r]);
      fac[r] = __expf(m[r] - mn);
      p0[r] = __expf(sv0[r] - mn);
      p1[r] = __expf(sv1[r] - mn);
      rs[r] = p0[r] + p1[r];
      m[r] = mn;
    }
    #pragma unroll
    for (int r = 0; r < 4; ++r) {
      rs[r] += __shfl_xor(rs[r], 1, 16);
      rs[r] += __shfl_xor(rs[r], 2, 16);
      rs[r] += __shfl_xor(rs[r], 4, 16);
      rs[r] += __shfl_xor(rs[r], 8, 16);
      lsum[r] = lsum[r] * fac[r] + rs[r];
    }
    #pragma unroll
    for (int nt = 0; nt < 6; ++nt)
      #pragma unroll
      for (int r = 0; r < 4; ++r) acc[nt][r] *= fac[r];

    // ---- P (D-layout) -> LDS -> A-frag (bf16) ----
    u16* Pw = Ps + wid * 640;
    #pragma unroll
    for (int r = 0; r < 4; ++r) {
      Pw[(kg * 4 + r) * 40 + ln] = f2bf(p0[r]);
      Pw[(kg * 4 + r) * 40 + 16 + ln] = f2bf(p1[r]);
    }
    s16x8 pa = *(const s16x8*)&Pw[ln * 40 + kg * 8];

    // ---- acc += P @ V ----
    #pragma unroll
    for (int nt = 0; nt < 6; ++nt) {
      s16x8 bv = *(const s16x8*)&Vt[(nt * 16 + ln) * 40 + kg * 8];
      acc[nt] = __builtin_amdgcn_mfma_f32_16x16x32_bf16(pa, bv, acc[nt], 0, 0, 0);
    }
    __syncthreads();
  }

  // ---- epilogue: out = acc / lsum + V ----
  int rowd = bb * LSEQ + bx * 32 + wid * 16 + kg * 4;
  float inv[4];
  #pragma unroll
  for (int r = 0; r < 4; ++r) inv[r] = 1.f / lsum[r];
  #pragma unroll
  for (int nt = 0; nt < 6; ++nt) {
    int col = nt * 16 + ln;
    #pragma unroll
    for (int r = 0; r < 4; ++r) {
      size_t oi = (size_t)(rowd + r) * 96 + col;
      out[oi] = acc[nt][r] * inv[r] + Vf[oi];
    }
  }
}

// ---------------------------------------------------------------------------
extern "C" void kernel_launch(void* const* d_in, const int* in_sizes, int n_in,
                              void* d_out, int out_size, void* d_ws,
                              size_t ws_size, hipStream_t stream) {
  const float* plm   = (const float*)d_in[0];
  const float* evo   = (const float*)d_in[1];
  const int* seqlen  = (const int*)d_in[2];
  const float* q_w   = (const float*)d_in[3];
  const float* q_b   = (const float*)d_in[4];
  const float* k_w   = (const float*)d_in[5];
  const float* k_b   = (const float*)d_in[6];
  const float* v_w   = (const float*)d_in[7];
  const float* v_b   = (const float*)d_in[8];
  const float* cn3_w = (const float*)d_in[9];
  const float* cn3_b = (const float*)d_in[10];
  const float* cn5_w = (const float*)d_in[11];
  const float* cn5_b = (const float*)d_in[12];

  char* ws = (char*)d_ws;
  u16* weff  = (u16*)(ws + 0);          // 96*2560*2      = 491520
  float* beff = (float*)(ws + 491520);  // 96*4
  u16* qwb   = (u16*)(ws + 492032);     // 96*512*2       = 98304
  u16* vwb   = (u16*)(ws + 590336);     // 96*1024*2      = 196608
  u16* Qb    = (u16*)(ws + 786944);     // 16384*96*2     = 3145728
  u16* Kb    = (u16*)(ws + 3932672);
  u16* Vb    = (u16*)(ws + 7078400);
  float* Vf  = (float*)(ws + 10224128); // 16384*96*4     = 6291456
  float* out = (float*)d_out;

  prep_kernel<<<1537, 256, 0, stream>>>(q_w, k_w, k_b, v_w, cn3_w, cn3_b,
                                        cn5_w, cn5_b, weff, beff, qwb, vwb);
  dim3 g(32, 8);
  proj_gemm<512, false><<<g, 256, 0, stream>>>(evo, qwb, q_b, Qb, nullptr);
  proj_gemm<1024, true><<<g, 256, 0, stream>>>(plm, vwb, v_b, Vb, Vf);
  proj_kconv<<<g, 256, 0, stream>>>(evo, weff, beff, Kb);
  attn_kernel<<<dim3(64, 8), 128, 0, stream>>>(Qb, Kb, Vb, Vf, seqlen, out);
}

// Round 2
// 207.573 us; speedup vs baseline: 1.5151x; 1.5151x over previous
//
#include <hip/hip_runtime.h>

typedef unsigned short u16;
typedef unsigned int u32;
typedef float f32x4 __attribute__((ext_vector_type(4)));
typedef short s16x8 __attribute__((ext_vector_type(8)));

#define LSEQ 2048
#define QIN 512
#define VIN 1024
#define KCAT 704
#define KEFF 2560
#define NORMS 0.10206207261596575f  // 1/sqrt(96)

__device__ __forceinline__ u16 f2bf(float f) {
  u32 u = __float_as_uint(f);
  u = (u + 0x7fffu + ((u >> 16) & 1u)) >> 16;  // RNE
  return (u16)u;
}

__device__ __forceinline__ s16x8 load8cvt(const float* __restrict__ p) {
  float4 a = *(const float4*)p;
  float4 b = *(const float4*)(p + 4);
  s16x8 r;
  r[0] = (short)f2bf(a.x); r[1] = (short)f2bf(a.y);
  r[2] = (short)f2bf(a.z); r[3] = (short)f2bf(a.w);
  r[4] = (short)f2bf(b.x); r[5] = (short)f2bf(b.y);
  r[6] = (short)f2bf(b.z); r[7] = (short)f2bf(b.w);
  return r;
}

// ---------------------------------------------------------------------------
// Kernel 1: fold conv3/conv5 + k_w into W_eff (96 x 2560 bf16) + b_eff, and
// convert q_w / v_w to bf16.  k index = t*512 + c, taps t=0..4 <-> offset t-2.
// ---------------------------------------------------------------------------
__global__ __launch_bounds__(256) void prep_kernel(
    const float* __restrict__ q_w, const float* __restrict__ k_w,
    const float* __restrict__ k_b, const float* __restrict__ v_w,
    const float* __restrict__ cn3_w, const float* __restrict__ cn3_b,
    const float* __restrict__ cn5_w, const float* __restrict__ cn5_b,
    u16* __restrict__ weff, float* __restrict__ beff,
    u16* __restrict__ qwb, u16* __restrict__ vwb) {
  int blk = blockIdx.x, tid = threadIdx.x;
  if (blk < 960) {                      // W_eff: 96*2560 = 245760 elems
    int e = blk * 256 + tid;
    int o = e / KEFF;
    int k = e % KEFF;
    int t = k >> 9;
    int c = k & 511;
    const float* kwo = k_w + o * KCAT;
    float acc = (t == 2) ? kwo[c] : 0.f;
    if (t >= 1 && t <= 3) {
      const float* c3 = cn3_w + c * 3 + (t - 1);   // cn3_w[j][c][t-1]
      #pragma unroll 8
      for (int j = 0; j < 96; ++j) acc += kwo[512 + j] * c3[j * 1536];
    }
    const float* c5 = cn5_w + c * 5 + t;           // cn5_w[j][c][t]
    #pragma unroll 8
    for (int j = 0; j < 96; ++j) acc += kwo[608 + j] * c5[j * 2560];
    weff[e] = f2bf(acc);
  } else if (blk == 960) {              // b_eff
    if (tid < 96) {
      const float* kwo = k_w + tid * KCAT;
      float b = k_b[tid];
      for (int j = 0; j < 96; ++j)
        b += kwo[512 + j] * cn3_b[j] + kwo[608 + j] * cn5_b[j];
      beff[tid] = b;
    }
  } else if (blk < 961 + 192) {         // q_w -> bf16 (49152)
    int i = (blk - 961) * 256 + tid;
    qwb[i] = f2bf(q_w[i]);
  } else {                              // v_w -> bf16 (98304)
    int i = (blk - 1153) * 256 + tid;
    vwb[i] = f2bf(v_w[i]);
  }
}

// ---------------------------------------------------------------------------
// Kernel 2: K-split projection GEMM.  Block = 16 output rows x 96 cols,
// NW waves; wave w owns K-slice [w*KPW, (w+1)*KPW).  For CONV (folded conv
// K-projection) wave w = tap w: A rows shifted by w-2, W cols w*512+c.
// Partials reduced via LDS.  grid (128, 8) -> 1024 blocks, NW*1024 waves.
// ---------------------------------------------------------------------------
template <int NW, int KPW, int AKD, bool CONV, bool WROUT, bool WRF32, bool WRVT>
__global__ __launch_bounds__(NW * 64) void proj_split(
    const float* __restrict__ X, const u16* __restrict__ W,
    const float* __restrict__ bias, u16* __restrict__ Out,
    float* __restrict__ OutF, u16* __restrict__ VtOut) {
  constexpr int WKD = NW * KPW;
  __shared__ float Ls[NW][16][97];
  int bx = blockIdx.x, bb = blockIdx.y;
  int tid = threadIdx.x;
  int wid = tid >> 6, lane = tid & 63, ln = lane & 15, kg = lane >> 4;
  int srow = bx * 16 + ln + (CONV ? wid - 2 : 0);
  bool rowok = (srow >= 0) && (srow < LSEQ);
  const float* xr = X + (size_t)(bb * LSEQ + (rowok ? srow : 0)) * AKD;
  f32x4 acc[6];
  #pragma unroll
  for (int nt = 0; nt < 6; ++nt) acc[nt] = (f32x4){0.f, 0.f, 0.f, 0.f};
  #pragma unroll 2
  for (int kc = 0; kc < KPW / 32; ++kc) {
    int kl = kc * 32 + kg * 8;
    int acol = CONV ? kl : wid * KPW + kl;
    int wcol = wid * KPW + kl;
    s16x8 a = (s16x8){0, 0, 0, 0, 0, 0, 0, 0};
    if (rowok) a = load8cvt(xr + acol);
    #pragma unroll
    for (int nt = 0; nt < 6; ++nt) {
      s16x8 bf = *(const s16x8*)&W[(size_t)(nt * 16 + ln) * WKD + wcol];
      acc[nt] = __builtin_amdgcn_mfma_f32_16x16x32_bf16(a, bf, acc[nt], 0, 0, 0);
    }
  }
  #pragma unroll
  for (int nt = 0; nt < 6; ++nt)
    #pragma unroll
    for (int r = 0; r < 4; ++r)
      Ls[wid][kg * 4 + r][nt * 16 + ln] = acc[nt][r];
  __syncthreads();
  size_t rbase = ((size_t)bb * LSEQ + bx * 16) * 96;
  if constexpr (WROUT || WRF32) {
    for (int i = tid; i < 1536; i += NW * 64) {
      int row = i / 96, col = i - row * 96;
      float s = bias[col];
      #pragma unroll
      for (int w = 0; w < NW; ++w) s += Ls[w][row][col];
      if constexpr (WROUT) Out[rbase + i] = f2bf(s);
      if constexpr (WRF32) OutF[rbase + i] = s;
    }
  }
  if constexpr (WRVT) {   // V transposed [b][vd][key], coalesced over keys
    size_t vtb = (size_t)bb * 96 * LSEQ + bx * 16;
    for (int i = tid; i < 1536; i += NW * 64) {
      int row = i & 15, col = i >> 4;
      float s = bias[col];
      #pragma unroll
      for (int w = 0; w < NW; ++w) s += Ls[w][row][col];
      VtOut[vtb + (size_t)col * LSEQ + row] = f2bf(s);
    }
  }
}

// ---------------------------------------------------------------------------
// Kernel 3: flash attention + "+V", key-split flash-decoding.
// grid (128, 8): 16 q-rows per block, 4 waves; wave w takes key-tiles
// kc % 4 == w (32 keys each).  K / Vt fragments read direct from global
// (per-batch K, Vt are L2-resident).  Partials combined via LDS.
// ---------------------------------------------------------------------------
__global__ __launch_bounds__(256) void attn_kernel(
    const u16* __restrict__ Qb, const u16* __restrict__ Kb,
    const u16* __restrict__ Vt, const float* __restrict__ Vf,
    const int* __restrict__ seqlen, float* __restrict__ out) {
  __shared__ u16 Ps[4][16][40];       // per-wave P scratch
  __shared__ float Cacc[4][16][97];   // partial O
  __shared__ float Cml[4][16][2];     // partial m, l

  int bx = blockIdx.x, bb = blockIdx.y;
  int tid = threadIdx.x;
  int wid = tid >> 6, lane = tid & 63, ln = lane & 15, kg = lane >> 4;
  int n = seqlen[bb];
  int nkc = (n + 31) >> 5;

  int qrow = bb * LSEQ + bx * 16 + ln;
  s16x8 aQ[3];
  #pragma unroll
  for (int kk = 0; kk < 3; ++kk)
    aQ[kk] = *(const s16x8*)&Qb[(size_t)qrow * 96 + kk * 32 + kg * 8];

  const u16* Kbase = Kb + (size_t)bb * LSEQ * 96;
  const u16* Vtb = Vt + (size_t)bb * 96 * LSEQ;

  float m[4], lsum[4];
  f32x4 acc[6];
  #pragma unroll
  for (int r = 0; r < 4; ++r) { m[r] = -1e30f; lsum[r] = 0.f; }
  #pragma unroll
  for (int nt = 0; nt < 6; ++nt) acc[nt] = (f32x4){0.f, 0.f, 0.f, 0.f};

  for (int kc = wid; kc < nkc; kc += 4) {
    int key0 = kc * 32;
    // ---- S = Q K^T, B-frags from global (L1/L2) ----
    f32x4 s0 = (f32x4){0.f, 0.f, 0.f, 0.f};
    f32x4 s1 = (f32x4){0.f, 0.f, 0.f, 0.f};
    #pragma unroll
    for (int kk = 0; kk < 3; ++kk) {
      s16x8 b0 = *(const s16x8*)&Kbase[(size_t)(key0 + ln) * 96 + kk * 32 + kg * 8];
      s0 = __builtin_amdgcn_mfma_f32_16x16x32_bf16(aQ[kk], b0, s0, 0, 0, 0);
      s16x8 b1 = *(const s16x8*)&Kbase[(size_t)(key0 + 16 + ln) * 96 + kk * 32 + kg * 8];
      s1 = __builtin_amdgcn_mfma_f32_16x16x32_bf16(aQ[kk], b1, s1, 0, 0, 0);
    }

    // ---- mask + scale, online softmax ----
    bool v0 = (key0 + ln) < n;
    bool v1 = (key0 + 16 + ln) < n;
    float sv0[4], sv1[4], mx[4];
    #pragma unroll
    for (int r = 0; r < 4; ++r) {
      sv0[r] = v0 ? s0[r] * NORMS : -1e30f;
      sv1[r] = v1 ? s1[r] * NORMS : -1e30f;
      mx[r] = fmaxf(sv0[r], sv1[r]);
    }
    #pragma unroll
    for (int r = 0; r < 4; ++r) {
      mx[r] = fmaxf(mx[r], __shfl_xor(mx[r], 1, 16));
      mx[r] = fmaxf(mx[r], __shfl_xor(mx[r], 2, 16));
      mx[r] = fmaxf(mx[r], __shfl_xor(mx[r], 4, 16));
      mx[r] = fmaxf(mx[r], __shfl_xor(mx[r], 8, 16));
    }
    float fac[4], p0[4], p1[4], rs[4];
    #pragma unroll
    for (int r = 0; r < 4; ++r) {
      float mn = fmaxf(m[r], mx[r]);
      fac[r] = __expf(m[r] - mn);
      p0[r] = __expf(sv0[r] - mn);
      p1[r] = __expf(sv1[r] - mn);
      rs[r] = p0[r] + p1[r];
      m[r] = mn;
    }
    #pragma unroll
    for (int r = 0; r < 4; ++r) {
      rs[r] += __shfl_xor(rs[r], 1, 16);
      rs[r] += __shfl_xor(rs[r], 2, 16);
      rs[r] += __shfl_xor(rs[r], 4, 16);
      rs[r] += __shfl_xor(rs[r], 8, 16);
      lsum[r] = lsum[r] * fac[r] + rs[r];
    }
    #pragma unroll
    for (int nt = 0; nt < 6; ++nt)
      #pragma unroll
      for (int r = 0; r < 4; ++r) acc[nt][r] *= fac[r];

    // ---- P (D-layout) -> per-wave LDS -> A-frag (bf16) ----
    u16* Pw = &Ps[wid][0][0];
    #pragma unroll
    for (int r = 0; r < 4; ++r) {
      Pw[(kg * 4 + r) * 40 + ln] = f2bf(p0[r]);
      Pw[(kg * 4 + r) * 40 + 16 + ln] = f2bf(p1[r]);
    }
    s16x8 pa = *(const s16x8*)&Pw[ln * 40 + kg * 8];

    // ---- acc += P @ V, B-frags contiguous from global Vt ----
    #pragma unroll
    for (int nt = 0; nt < 6; ++nt) {
      s16x8 bv = *(const s16x8*)&Vtb[(size_t)(nt * 16 + ln) * LSEQ + key0 + kg * 8];
      acc[nt] = __builtin_amdgcn_mfma_f32_16x16x32_bf16(pa, bv, acc[nt], 0, 0, 0);
    }
  }

  // ---- write partials ----
  #pragma unroll
  for (int nt = 0; nt < 6; ++nt)
    #pragma unroll
    for (int r = 0; r < 4; ++r)
      Cacc[wid][kg * 4 + r][nt * 16 + ln] = acc[nt][r];
  if (ln == 0) {
    #pragma unroll
    for (int r = 0; r < 4; ++r) {
      Cml[wid][kg * 4 + r][0] = m[r];
      Cml[wid][kg * 4 + r][1] = lsum[r];
    }
  }
  __syncthreads();

  // ---- combine 4 key-split partials + "+V" ----
  size_t obase = ((size_t)bb * LSEQ + bx * 16) * 96;
  for (int i = tid; i < 1536; i += 256) {
    int row = i / 96, col = i - row * 96;
    float mg = -1e30f;
    #pragma unroll
    for (int w = 0; w < 4; ++w) mg = fmaxf(mg, Cml[w][row][0]);
    float lg = 0.f, av = 0.f;
    #pragma unroll
    for (int w = 0; w < 4; ++w) {
      float e = __expf(Cml[w][row][0] - mg);
      lg += Cml[w][row][1] * e;
      av += Cacc[w][row][col] * e;
    }
    out[obase + i] = av / lg + Vf[obase + i];
  }
}

// ---------------------------------------------------------------------------
extern "C" void kernel_launch(void* const* d_in, const int* in_sizes, int n_in,
                              void* d_out, int out_size, void* d_ws,
                              size_t ws_size, hipStream_t stream) {
  const float* plm   = (const float*)d_in[0];
  const float* evo   = (const float*)d_in[1];
  const int* seqlen  = (const int*)d_in[2];
  const float* q_w   = (const float*)d_in[3];
  const float* q_b   = (const float*)d_in[4];
  const float* k_w   = (const float*)d_in[5];
  const float* k_b   = (const float*)d_in[6];
  const float* v_w   = (const float*)d_in[7];
  const float* v_b   = (const float*)d_in[8];
  const float* cn3_w = (const float*)d_in[9];
  const float* cn3_b = (const float*)d_in[10];
  const float* cn5_w = (const float*)d_in[11];
  const float* cn5_b = (const float*)d_in[12];

  char* ws = (char*)d_ws;
  u16* weff   = (u16*)(ws + 0);          // 491520
  float* beff = (float*)(ws + 491520);   // 512
  u16* qwb    = (u16*)(ws + 492032);     // 98304
  u16* vwb    = (u16*)(ws + 590336);     // 196608
  u16* Qb     = (u16*)(ws + 786944);     // 3145728
  u16* Kb     = (u16*)(ws + 3932672);    // 3145728
  u16* Vt     = (u16*)(ws + 7078400);    // 3145728 (V transposed [b][vd][key])
  float* Vf   = (float*)(ws + 10224128); // 6291456 (V f32 row-major)
  float* out  = (float*)d_out;

  prep_kernel<<<1537, 256, 0, stream>>>(q_w, k_w, k_b, v_w, cn3_w, cn3_b,
                                        cn5_w, cn5_b, weff, beff, qwb, vwb);
  dim3 g(128, 8);
  proj_split<4, 128, QIN, false, true, false, false>
      <<<g, 256, 0, stream>>>(evo, qwb, q_b, Qb, nullptr, nullptr);
  proj_split<4, 256, VIN, false, false, true, true>
      <<<g, 256, 0, stream>>>(plm, vwb, v_b, nullptr, Vf, Vt);
  proj_split<5, 512, QIN, true, true, false, false>
      <<<g, 320, 0, stream>>>(evo, weff, beff, Kb, nullptr, nullptr);
  attn_kernel<<<g, 256, 0, stream>>>(Qb, Kb, Vt, Vf, seqlen, out);
}

// Round 3
// 122.627 us; speedup vs baseline: 2.5647x; 1.6927x over previous
//
#include <hip/hip_runtime.h>

typedef unsigned short u16;
typedef unsigned int u32;
typedef float f32x4 __attribute__((ext_vector_type(4)));
typedef short s16x8 __attribute__((ext_vector_type(8)));

#define LSEQ 2048
#define QIN 512
#define VIN 1024
#define KCAT 704
#define KEFF 2560
#define NORMS 0.10206207261596575f  // 1/sqrt(96)

__device__ __forceinline__ u16 f2bf(float f) {
  u32 u = __float_as_uint(f);
  u = (u + 0x7fffu + ((u >> 16) & 1u)) >> 16;  // RNE
  return (u16)u;
}
__device__ __forceinline__ float bf2f(u16 v) {
  return __uint_as_float(((u32)v) << 16);
}

__device__ __forceinline__ s16x8 load8cvt(const float* __restrict__ p) {
  float4 a = *(const float4*)p;
  float4 b = *(const float4*)(p + 4);
  s16x8 r;
  r[0] = (short)f2bf(a.x); r[1] = (short)f2bf(a.y);
  r[2] = (short)f2bf(a.z); r[3] = (short)f2bf(a.w);
  r[4] = (short)f2bf(b.x); r[5] = (short)f2bf(b.y);
  r[6] = (short)f2bf(b.z); r[7] = (short)f2bf(b.w);
  return r;
}

// Fragment-linear index for a weight matrix W[N=96][K]:
// element W[o][k] -> ((kc*6 + nt)*64 + kg*16 + ln)*8 + j
// kc=k/32, kg=(k%32)/8, j=k%8, nt=o/16, ln=o%16.
__device__ __forceinline__ size_t wfrag_idx(int o, int k) {
  int kc = k >> 5, kg = (k >> 3) & 3, j = k & 7;
  int nt = o >> 4, ln = o & 15;
  return ((size_t)(kc * 6 + nt) * 64 + kg * 16 + ln) * 8 + j;
}

// ---------------------------------------------------------------------------
// Kernel 1: prep.  Folds conv3/conv5+k_w into W_eff (frag layout), converts
// q_w/v_w to frag-bf16, converts evo to bf16 row-major.
// blocks: [0,960) W_eff, 960 b_eff, [961,1153) q_w, [1153,1537) v_w,
//         [1537,5633) evob.
// ---------------------------------------------------------------------------
__global__ __launch_bounds__(256) void prep_kernel(
    const float* __restrict__ q_w, const float* __restrict__ k_w,
    const float* __restrict__ k_b, const float* __restrict__ v_w,
    const float* __restrict__ cn3_w, const float* __restrict__ cn3_b,
    const float* __restrict__ cn5_w, const float* __restrict__ cn5_b,
    const float* __restrict__ evo,
    u16* __restrict__ wefff, float* __restrict__ beff,
    u16* __restrict__ qwf, u16* __restrict__ vwf, u16* __restrict__ evob) {
  int blk = blockIdx.x, tid = threadIdx.x;
  if (blk < 960) {                      // W_eff: 96*2560 elems
    int e = blk * 256 + tid;
    int o = e / KEFF;
    int k = e % KEFF;
    int t = k >> 9;
    int c = k & 511;
    const float* kwo = k_w + o * KCAT;
    float acc = (t == 2) ? kwo[c] : 0.f;
    if (t >= 1 && t <= 3) {
      const float* c3 = cn3_w + c * 3 + (t - 1);   // cn3_w[j][c][t-1]
      #pragma unroll 8
      for (int j = 0; j < 96; ++j) acc += kwo[512 + j] * c3[j * 1536];
    }
    const float* c5 = cn5_w + c * 5 + t;           // cn5_w[j][c][t]
    #pragma unroll 8
    for (int j = 0; j < 96; ++j) acc += kwo[608 + j] * c5[j * 2560];
    wefff[wfrag_idx(o, k)] = f2bf(acc);
  } else if (blk == 960) {              // b_eff
    if (tid < 96) {
      const float* kwo = k_w + tid * KCAT;
      float b = k_b[tid];
      for (int j = 0; j < 96; ++j)
        b += kwo[512 + j] * cn3_b[j] + kwo[608 + j] * cn5_b[j];
      beff[tid] = b;
    }
  } else if (blk < 1153) {              // q_w -> frag bf16 (96*512)
    int e = (blk - 961) * 256 + tid;
    int o = e >> 9, k = e & 511;
    qwf[wfrag_idx(o, k)] = f2bf(q_w[e]);
  } else if (blk < 1537) {              // v_w -> frag bf16 (96*1024)
    int e = (blk - 1153) * 256 + tid;
    int o = e >> 10, k = e & 1023;
    vwf[wfrag_idx(o, k)] = f2bf(v_w[e]);
  } else {                              // evo f32 -> bf16 (8M elems, 8/thread)
    size_t e8 = (size_t)(blk - 1537) * 256 + tid;
    const float* src = evo + e8 * 8;
    float4 a = *(const float4*)src;
    float4 b = *(const float4*)(src + 4);
    s16x8 r;
    r[0] = (short)f2bf(a.x); r[1] = (short)f2bf(a.y);
    r[2] = (short)f2bf(a.z); r[3] = (short)f2bf(a.w);
    r[4] = (short)f2bf(b.x); r[5] = (short)f2bf(b.y);
    r[6] = (short)f2bf(b.z); r[7] = (short)f2bf(b.w);
    *(s16x8*)(evob + e8 * 8) = r;
  }
}

// ---------------------------------------------------------------------------
// Kernel 2: K-split projection GEMM, frag-layout weights, frag-layout output.
// Block = 16 output rows; NW waves each own a K-slice (MODE 1: one conv tap).
// MODE 0: Q (A=evob, out Qfrag); MODE 1: K-conv (A=evob shifted, out Kfrag);
// MODE 2: V (A=plm f32, out Vfrag + Vb row-major bf16).
// ---------------------------------------------------------------------------
template <int NW, int KPW, int AKD, int MODE, int UNR>
__global__ __launch_bounds__(NW * 64, 2) void proj_split(
    const float* __restrict__ Xf, const u16* __restrict__ Xb,
    const u16* __restrict__ Wf, const float* __restrict__ bias,
    u16* __restrict__ OutFrag, u16* __restrict__ Vb) {
  __shared__ float Ls[NW][16][97];
  int bx = blockIdx.x, bb = blockIdx.y;
  int tid = threadIdx.x;
  int wid = tid >> 6, lane = tid & 63, ln = lane & 15, kg = lane >> 4;
  int srow = bx * 16 + ln + (MODE == 1 ? wid - 2 : 0);
  bool rowok = (srow >= 0) && (srow < LSEQ);
  f32x4 acc[6];
  #pragma unroll
  for (int nt = 0; nt < 6; ++nt) acc[nt] = (f32x4){0.f, 0.f, 0.f, 0.f};

  const u16* xb = Xb + ((size_t)bb * LSEQ + (rowok ? srow : 0)) * AKD;
  const float* xf = Xf + ((size_t)bb * LSEQ + bx * 16 + ln) * AKD;

  #pragma unroll UNR
  for (int kc = 0; kc < KPW / 32; ++kc) {
    s16x8 a;
    if constexpr (MODE == 0) {
      a = *(const s16x8*)&xb[wid * KPW + kc * 32 + kg * 8];
    } else if constexpr (MODE == 1) {
      if (rowok)
        a = *(const s16x8*)&xb[kc * 32 + kg * 8];
      else
        a = (s16x8){0, 0, 0, 0, 0, 0, 0, 0};
    } else {
      a = load8cvt(xf + wid * KPW + kc * 32 + kg * 8);
    }
    int kcg = wid * (KPW / 32) + kc;
    const u16* wp = Wf + ((size_t)kcg * 6 * 64) * 8 + lane * 8;
    #pragma unroll
    for (int nt = 0; nt < 6; ++nt) {
      s16x8 bf = *(const s16x8*)&wp[(size_t)nt * 512];
      acc[nt] = __builtin_amdgcn_mfma_f32_16x16x32_bf16(a, bf, acc[nt], 0, 0, 0);
    }
  }
  #pragma unroll
  for (int nt = 0; nt < 6; ++nt)
    #pragma unroll
    for (int r = 0; r < 4; ++r)
      Ls[wid][kg * 4 + r][nt * 16 + ln] = acc[nt][r];
  __syncthreads();

  for (int i = tid; i < 1536; i += NW * 64) {
    int r = i / 96, c = i - r * 96;
    float s = bias[c];
    #pragma unroll
    for (int w = 0; w < NW; ++w) s += Ls[w][r][c];
    u16 sb = f2bf(s);
    if constexpr (MODE == 0 || MODE == 1) {
      // Qfrag/Kfrag: tile = 16 rows; element [row=ln][feat c]
      int kk = c >> 5, kg2 = (c >> 3) & 3, j = c & 7;
      size_t qt = (size_t)bb * 128 + bx;
      OutFrag[((qt * 3 + kk) * 64 + kg2 * 16 + r) * 8 + j] = sb;
    } else {
      // Vfrag: element V[key][c] at [b][key/32][nt=c/16][kg*16+ln][j]
      int key = bx * 16 + r;
      int ktv = key >> 5, kgv = (key >> 3) & 3, jv = key & 7;
      int nt = c >> 4, lnv = c & 15;
      OutFrag[((((size_t)bb * 64 + ktv) * 6 + nt) * 64 + kgv * 16 + lnv) * 8 + jv] = sb;
      Vb[((size_t)bb * LSEQ + key) * 96 + c] = sb;
    }
  }
}

// ---------------------------------------------------------------------------
// Kernel 3: flash attention + "+V", key-split across 4 waves, all operands in
// fragment layout -> every global load is a coalesced 1KB wave load.
// 1D grid 1024, XCD-swizzled so each batch lives on one XCD's L2.
// ---------------------------------------------------------------------------
__global__ __launch_bounds__(256) void attn_kernel(
    const u16* __restrict__ Qf, const u16* __restrict__ Kf,
    const u16* __restrict__ Vfr, const u16* __restrict__ Vb,
    const int* __restrict__ seqlen, float* __restrict__ out) {
  __shared__ u16 Ps[4][16][40];       // per-wave P scratch
  __shared__ float Cacc[4][16][97];   // partial O
  __shared__ float Cml[4][16][2];     // partial m, l

  int bid = blockIdx.x;
  int swz = (bid & 7) * 128 + (bid >> 3);   // XCD x -> batch x
  int bb = swz >> 7, bx = swz & 127;
  int tid = threadIdx.x;
  int wid = tid >> 6, lane = tid & 63, ln = lane & 15, kg = lane >> 4;
  int n = seqlen[bb];
  int nkc = (n + 31) >> 5;

  size_t qt = (size_t)bb * 128 + bx;
  s16x8 aQ[3];
  #pragma unroll
  for (int kk = 0; kk < 3; ++kk)
    aQ[kk] = *(const s16x8*)&Qf[((qt * 3 + kk) * 64 + lane) * 8];

  float m[4], lsum[4];
  f32x4 acc[6];
  #pragma unroll
  for (int r = 0; r < 4; ++r) { m[r] = -1e30f; lsum[r] = 0.f; }
  #pragma unroll
  for (int nt = 0; nt < 6; ++nt) acc[nt] = (f32x4){0.f, 0.f, 0.f, 0.f};

  for (int kc = wid; kc < nkc; kc += 4) {
    int key0 = kc * 32;
    // ---- S = Q K^T; K-frags: two 16-key tiles, 3KB contiguous each ----
    const u16* kf0 = Kf + (((size_t)bb * 128 + kc * 2) * 3 * 64) * 8 + lane * 8;
    f32x4 s0 = (f32x4){0.f, 0.f, 0.f, 0.f};
    f32x4 s1 = (f32x4){0.f, 0.f, 0.f, 0.f};
    #pragma unroll
    for (int kk = 0; kk < 3; ++kk) {
      s16x8 b0 = *(const s16x8*)&kf0[(size_t)kk * 512];
      s0 = __builtin_amdgcn_mfma_f32_16x16x32_bf16(aQ[kk], b0, s0, 0, 0, 0);
      s16x8 b1 = *(const s16x8*)&kf0[(size_t)(3 + kk) * 512];
      s1 = __builtin_amdgcn_mfma_f32_16x16x32_bf16(aQ[kk], b1, s1, 0, 0, 0);
    }

    // ---- mask + scale, online softmax ----
    bool v0 = (key0 + ln) < n;
    bool v1 = (key0 + 16 + ln) < n;
    float sv0[4], sv1[4], mx[4];
    #pragma unroll
    for (int r = 0; r < 4; ++r) {
      sv0[r] = v0 ? s0[r] * NORMS : -1e30f;
      sv1[r] = v1 ? s1[r] * NORMS : -1e30f;
      mx[r] = fmaxf(sv0[r], sv1[r]);
    }
    #pragma unroll
    for (int r = 0; r < 4; ++r) {
      mx[r] = fmaxf(mx[r], __shfl_xor(mx[r], 1, 16));
      mx[r] = fmaxf(mx[r], __shfl_xor(mx[r], 2, 16));
      mx[r] = fmaxf(mx[r], __shfl_xor(mx[r], 4, 16));
      mx[r] = fmaxf(mx[r], __shfl_xor(mx[r], 8, 16));
    }
    float fac[4], p0[4], p1[4], rs[4];
    #pragma unroll
    for (int r = 0; r < 4; ++r) {
      float mn = fmaxf(m[r], mx[r]);
      fac[r] = __expf(m[r] - mn);
      p0[r] = __expf(sv0[r] - mn);
      p1[r] = __expf(sv1[r] - mn);
      rs[r] = p0[r] + p1[r];
      m[r] = mn;
    }
    #pragma unroll
    for (int r = 0; r < 4; ++r) {
      rs[r] += __shfl_xor(rs[r], 1, 16);
      rs[r] += __shfl_xor(rs[r], 2, 16);
      rs[r] += __shfl_xor(rs[r], 4, 16);
      rs[r] += __shfl_xor(rs[r], 8, 16);
      lsum[r] = lsum[r] * fac[r] + rs[r];
    }
    #pragma unroll
    for (int nt = 0; nt < 6; ++nt)
      #pragma unroll
      for (int r = 0; r < 4; ++r) acc[nt][r] *= fac[r];

    // ---- P (D-layout) -> per-wave LDS -> A-frag (bf16) ----
    u16* Pw = &Ps[wid][0][0];
    #pragma unroll
    for (int r = 0; r < 4; ++r) {
      Pw[(kg * 4 + r) * 40 + ln] = f2bf(p0[r]);
      Pw[(kg * 4 + r) * 40 + 16 + ln] = f2bf(p1[r]);
    }
    s16x8 pa = *(const s16x8*)&Pw[ln * 40 + kg * 8];

    // ---- acc += P @ V; V-frags 6KB contiguous ----
    const u16* vf = Vfr + (((size_t)bb * 64 + kc) * 6 * 64) * 8 + lane * 8;
    #pragma unroll
    for (int nt = 0; nt < 6; ++nt) {
      s16x8 bv = *(const s16x8*)&vf[(size_t)nt * 512];
      acc[nt] = __builtin_amdgcn_mfma_f32_16x16x32_bf16(pa, bv, acc[nt], 0, 0, 0);
    }
  }

  // ---- write partials ----
  #pragma unroll
  for (int nt = 0; nt < 6; ++nt)
    #pragma unroll
    for (int r = 0; r < 4; ++r)
      Cacc[wid][kg * 4 + r][nt * 16 + ln] = acc[nt][r];
  if (ln == 0) {
    #pragma unroll
    for (int r = 0; r < 4; ++r) {
      Cml[wid][kg * 4 + r][0] = m[r];
      Cml[wid][kg * 4 + r][1] = lsum[r];
    }
  }
  __syncthreads();

  // ---- combine 4 key-split partials + "+V" ----
  size_t obase = ((size_t)bb * LSEQ + bx * 16) * 96;
  for (int i = tid; i < 1536; i += 256) {
    int row = i / 96;
    float mg = -1e30f;
    #pragma unroll
    for (int w = 0; w < 4; ++w) mg = fmaxf(mg, Cml[w][row][0]);
    float lg = 0.f, av = 0.f;
    #pragma unroll
    for (int w = 0; w < 4; ++w) {
      float e = __expf(Cml[w][row][0] - mg);
      lg += Cml[w][row][1] * e;
      av += Cacc[w][row][i - row * 96] * e;
    }
    out[obase + i] = av / lg + bf2f(Vb[obase + i]);
  }
}

// ---------------------------------------------------------------------------
extern "C" void kernel_launch(void* const* d_in, const int* in_sizes, int n_in,
                              void* d_out, int out_size, void* d_ws,
                              size_t ws_size, hipStream_t stream) {
  const float* plm   = (const float*)d_in[0];
  const float* evo   = (const float*)d_in[1];
  const int* seqlen  = (const int*)d_in[2];
  const float* q_w   = (const float*)d_in[3];
  const float* q_b   = (const float*)d_in[4];
  const float* k_w   = (const float*)d_in[5];
  const float* k_b   = (const float*)d_in[6];
  const float* v_w   = (const float*)d_in[7];
  const float* v_b   = (const float*)d_in[8];
  const float* cn3_w = (const float*)d_in[9];
  const float* cn3_b = (const float*)d_in[10];
  const float* cn5_w = (const float*)d_in[11];
  const float* cn5_b = (const float*)d_in[12];

  char* ws = (char*)d_ws;
  u16* wefff  = (u16*)(ws + 0);          // 491520
  float* beff = (float*)(ws + 491520);   // 512
  u16* qwf    = (u16*)(ws + 492032);     // 98304
  u16* vwf    = (u16*)(ws + 590336);     // 196608
  u16* Qf     = (u16*)(ws + 786944);     // 3145728 (Q frag layout)
  u16* Kf     = (u16*)(ws + 3932672);    // 3145728 (K frag layout)
  u16* Vfr    = (u16*)(ws + 7078400);    // 3145728 (V frag layout)
  u16* Vb     = (u16*)(ws + 10224128);   // 3145728 (V row-major bf16)
  u16* evob   = (u16*)(ws + 13369856);   // 16777216 (evo bf16)
  float* out  = (float*)d_out;

  prep_kernel<<<5633, 256, 0, stream>>>(q_w, k_w, k_b, v_w, cn3_w, cn3_b,
                                        cn5_w, cn5_b, evo, wefff, beff, qwf,
                                        vwf, evob);
  dim3 g(128, 8);
  proj_split<4, 128, QIN, 0, 4><<<g, 256, 0, stream>>>(
      nullptr, evob, qwf, q_b, Qf, nullptr);
  proj_split<4, 256, VIN, 2, 4><<<g, 256, 0, stream>>>(
      plm, nullptr, vwf, v_b, Vfr, Vb);
  proj_split<5, 512, QIN, 1, 4><<<g, 320, 0, stream>>>(
      nullptr, evob, wefff, beff, Kf, nullptr);
  attn_kernel<<<1024, 256, 0, stream>>>(Qf, Kf, Vfr, Vb, seqlen, out);
}